// Round 6
// baseline (33.299 us; speedup 1.0000x reference)
//
#include <hip/hip_runtime.h>

// Problem constants (fixed by reference setup_inputs): D=32 detectors,
// in_s = out_s = 64, row stride 2048 floats, B = 8192.
#define NDET    32
#define SEG     64
#define ROWLEN  2048
#define TILE_B  128
#define THREADS 256
#define LSTRIDE 72   // LDS row stride in bf16 (144 B, 16B-aligned, padded)

typedef __bf16 bf16x8 __attribute__((ext_vector_type(8)));
typedef __bf16 bf16x4 __attribute__((ext_vector_type(4)));
typedef float  f32x4  __attribute__((ext_vector_type(4)));

__device__ __forceinline__ bf16x4 cvt4(f32x4 a) {
  bf16x4 r;
  r[0] = (__bf16)a[0]; r[1] = (__bf16)a[1]; r[2] = (__bf16)a[2]; r[3] = (__bf16)a[3];
  return r;
}

__device__ __forceinline__ bf16x8 cvt8(f32x4 a, f32x4 b) {
  bf16x8 r;
  r[0] = (__bf16)a[0]; r[1] = (__bf16)a[1]; r[2] = (__bf16)a[2]; r[3] = (__bf16)a[3];
  r[4] = (__bf16)b[0]; r[5] = (__bf16)b[1]; r[6] = (__bf16)b[2]; r[7] = (__bf16)b[3];
  return r;
}

// y[b, d*64+o] = sum_i x[b, d*64+i] * W[d*64+o, d*64+i]
//
// v6 = r4 skeleton with two changes:
//  * NO __syncthreads: each wave stages/reads only its own 32 LDS rows, so
//    an intra-wave s_waitcnt lgkmcnt(0) replaces the block barrier -> the 4
//    waves run as independent pipelines (no vmcnt(0) block-wide drain).
//  * W fragments straight to registers (L2-hot, 16KB/block) -> LDS 18.4 KB,
//    8 blocks/CU by LDS. Plain stores (nt caused 23% write amplification).
__global__ __launch_bounds__(THREADS) void ensemble_linear_v6(
    const float* __restrict__ x, const float* __restrict__ W,
    float* __restrict__ y) {
  const int d     = blockIdx.y;
  const int b0    = blockIdx.x * TILE_B;
  const int t     = threadIdx.x;
  const int lane  = t & 63;
  const int wid   = t >> 6;        // 0..3
  const int dbase = d * SEG;

  const int rq  = lane >> 4;       // staging: row within 4-row quad
  const int c4  = lane & 15;       // staging: 16B chunk within 256B row
  const int m16 = lane & 15;       // fragment M/N index
  const int kg  = lane >> 4;       // fragment k-group

  __shared__ __bf16 xls[TILE_B * LSTRIDE];   // 18432 B; wave wid owns rows wid*32..+31

  // ---- issue all 8 x loads up front (coalesced: 4 complete 256B rows/instr) ----
  f32x4 xv[8];
#pragma unroll
  for (int p = 0; p < 8; ++p) {
    const int row = wid * 32 + p * 4 + rq;
    xv[p] = *(const f32x4*)(x + (size_t)(b0 + row) * ROWLEN + dbase + c4 * 4);
  }

  // ---- W fragments direct to registers (L2-hot; once per block) ----
  // lane holds W[dbase + g*16 + m16][dbase + kh*32 + kg*8 + j], j=0..7
  bf16x8 wfrag[4][2];
#pragma unroll
  for (int g = 0; g < 4; ++g) {
    const float* wp = W + (size_t)(dbase + g * 16 + m16) * ROWLEN + dbase + kg * 8;
    f32x4 wa0 = *(const f32x4*)(wp);
    f32x4 wa1 = *(const f32x4*)(wp + 4);
    f32x4 wb0 = *(const f32x4*)(wp + 32);
    f32x4 wb1 = *(const f32x4*)(wp + 36);
    wfrag[g][0] = cvt8(wa0, wa1);
    wfrag[g][1] = cvt8(wb0, wb1);
  }

  // ---- convert + stage x to this wave's LDS rows ----
#pragma unroll
  for (int p = 0; p < 8; ++p) {
    const int row = wid * 32 + p * 4 + rq;
    *(bf16x4*)(&xls[row * LSTRIDE + c4 * 4]) = cvt4(xv[p]);
  }

  // Intra-wave only: all our ds_writes retired before our ds_reads issue.
  asm volatile("s_waitcnt lgkmcnt(0)" ::: "memory");

  // ---- compute: wave owns rows [wid*32, wid*32+32), 2 sub-tiles of 16 ----
  // Swapped-operand MFMA (r3-verified): D = W_tile . x_tile^T.
#pragma unroll
  for (int s = 0; s < 2; ++s) {
    const int rbase = wid * 32 + s * 16;
    bf16x8 a0 = *(const bf16x8*)(&xls[(rbase + m16) * LSTRIDE + kg * 8]);        // k 0..31
    bf16x8 a1 = *(const bf16x8*)(&xls[(rbase + m16) * LSTRIDE + 32 + kg * 8]);   // k 32..63

    float* yp = y + (size_t)(b0 + rbase + m16) * ROWLEN + dbase + kg * 4;
#pragma unroll
    for (int g = 0; g < 4; ++g) {
      f32x4 acc = (f32x4){0.f, 0.f, 0.f, 0.f};
      acc = __builtin_amdgcn_mfma_f32_16x16x32_bf16(wfrag[g][0], a0, acc, 0, 0, 0);
      acc = __builtin_amdgcn_mfma_f32_16x16x32_bf16(wfrag[g][1], a1, acc, 0, 0, 0);
      *(f32x4*)(yp + g * 16) = acc;
    }
  }
}

extern "C" void kernel_launch(void* const* d_in, const int* in_sizes, int n_in,
                              void* d_out, int out_size, void* d_ws, size_t ws_size,
                              hipStream_t stream) {
  const float* x = (const float*)d_in[0];
  const float* W = (const float*)d_in[1];
  float* y = (float*)d_out;
  const int B = in_sizes[0] / ROWLEN;   // 8192
  dim3 grid(B / TILE_B, NDET);
  ensemble_linear_v6<<<grid, dim3(THREADS), 0, stream>>>(x, W, y);
}

// Round 7
// 30.048 us; speedup vs baseline: 1.1082x; 1.1082x over previous
//
#include <hip/hip_runtime.h>

// Problem constants (fixed by reference setup_inputs): D=32 detectors,
// in_s = out_s = 64, row stride 2048 floats, B = 8192.
#define NDET    32
#define SEG     64
#define ROWLEN  2048
#define TILE_B  128
#define NITER   4              // tiles per block; block covers 512 rows
#define THREADS 256
#define LSTRIDE 72             // LDS row stride in bf16 (144 B, padded)

typedef __bf16 bf16x8 __attribute__((ext_vector_type(8)));
typedef __bf16 bf16x4 __attribute__((ext_vector_type(4)));
typedef float  f32x4  __attribute__((ext_vector_type(4)));

__device__ __forceinline__ bf16x4 cvt4(f32x4 a) {
  bf16x4 r;
  r[0] = (__bf16)a[0]; r[1] = (__bf16)a[1]; r[2] = (__bf16)a[2]; r[3] = (__bf16)a[3];
  return r;
}

__device__ __forceinline__ bf16x8 cvt8(f32x4 a, f32x4 b) {
  bf16x8 r;
  r[0] = (__bf16)a[0]; r[1] = (__bf16)a[1]; r[2] = (__bf16)a[2]; r[3] = (__bf16)a[3];
  r[4] = (__bf16)b[0]; r[5] = (__bf16)b[1]; r[6] = (__bf16)b[2]; r[7] = (__bf16)b[3];
  return r;
}

// y[b, d*64+o] = sum_i x[b, d*64+i] * W[d*64+o, d*64+i]
//
// v7: long-lived pipelined blocks. Each block = 4 waves, NITER=4 tiles of
// 128 rows. Depth-2 register prefetch: while computing tile t, loads for
// t+1 and t+2 are in flight (16KB/wave outstanding, continuously).
// Wave-private LDS slices (rows wid*32..+31), no barriers. Staging loads
// use the coalesced optimum (each 16-lane group reads one complete 256B
// row window). Swapped-operand MFMA (r3-verified): D = W_tile . x_tile^T.
__global__ __launch_bounds__(THREADS) void ensemble_linear_v7(
    const float* __restrict__ x, const float* __restrict__ W,
    float* __restrict__ y) {
  const int d     = blockIdx.y;
  const int b0    = blockIdx.x * (TILE_B * NITER);
  const int t     = threadIdx.x;
  const int lane  = t & 63;
  const int wid   = t >> 6;        // 0..3
  const int dbase = d * SEG;

  const int rq  = lane >> 4;       // staging: row within 4-row quad
  const int c4  = lane & 15;       // staging: 16B chunk within 256B row
  const int m16 = lane & 15;       // fragment M/N index
  const int kg  = lane >> 4;       // fragment k-group

  __shared__ __bf16 xls[TILE_B * LSTRIDE];   // 18432 B; wave-private slices

  const int srow = wid * 32 + rq;  // this thread's staging row base (+p*4)
  const float* xbase = x + (size_t)(b0 + srow) * ROWLEN + dbase + c4 * 4;

  // ---- prologue: issue x loads for tiles 0 and 1 (16 KB/wave in flight) ----
  f32x4 xv[2][8];
#pragma unroll
  for (int p = 0; p < 8; ++p)
    xv[0][p] = *(const f32x4*)(xbase + (size_t)(p * 4) * ROWLEN);
#pragma unroll
  for (int p = 0; p < 8; ++p)
    xv[1][p] = *(const f32x4*)(xbase + (size_t)(TILE_B + p * 4) * ROWLEN);

  // ---- W fragments direct to registers (once per block, 4 tiles amortize) ----
  bf16x8 wfrag[4][2];
#pragma unroll
  for (int g = 0; g < 4; ++g) {
    const float* wp = W + (size_t)(dbase + g * 16 + m16) * ROWLEN + dbase + kg * 8;
    f32x4 wa0 = *(const f32x4*)(wp);
    f32x4 wa1 = *(const f32x4*)(wp + 4);
    f32x4 wb0 = *(const f32x4*)(wp + 32);
    f32x4 wb1 = *(const f32x4*)(wp + 36);
    wfrag[g][0] = cvt8(wa0, wa1);
    wfrag[g][1] = cvt8(wb0, wb1);
  }

  // ---- pipelined tile loop (fully unrolled; xv index static) ----
#pragma unroll
  for (int tt = 0; tt < NITER; ++tt) {
    const int cur = tt & 1;

    // stage tile tt (compiler inserts the vmcnt wait for xv[cur])
#pragma unroll
    for (int p = 0; p < 8; ++p)
      *(bf16x4*)(&xls[(srow + p * 4) * LSTRIDE + c4 * 4]) = cvt4(xv[cur][p]);

    // prefetch tile tt+2 into the freed buffer
    if (tt + 2 < NITER) {
#pragma unroll
      for (int p = 0; p < 8; ++p)
        xv[cur][p] = *(const f32x4*)(xbase + (size_t)((tt + 2) * TILE_B + p * 4) * ROWLEN);
    }

    // intra-wave: our ds_writes retired before our ds_reads issue
    asm volatile("s_waitcnt lgkmcnt(0)" ::: "memory");

    // compute + store: wave owns rows [wid*32, wid*32+32) of this tile
#pragma unroll
    for (int s = 0; s < 2; ++s) {
      const int rbase = wid * 32 + s * 16;
      bf16x8 a0 = *(const bf16x8*)(&xls[(rbase + m16) * LSTRIDE + kg * 8]);       // k 0..31
      bf16x8 a1 = *(const bf16x8*)(&xls[(rbase + m16) * LSTRIDE + 32 + kg * 8]);  // k 32..63

      float* yp = y + (size_t)(b0 + tt * TILE_B + rbase + m16) * ROWLEN + dbase + kg * 4;
#pragma unroll
      for (int g = 0; g < 4; ++g) {
        f32x4 acc = (f32x4){0.f, 0.f, 0.f, 0.f};
        acc = __builtin_amdgcn_mfma_f32_16x16x32_bf16(wfrag[g][0], a0, acc, 0, 0, 0);
        acc = __builtin_amdgcn_mfma_f32_16x16x32_bf16(wfrag[g][1], a1, acc, 0, 0, 0);
        *(f32x4*)(yp + g * 16) = acc;
      }
    }
  }
}

extern "C" void kernel_launch(void* const* d_in, const int* in_sizes, int n_in,
                              void* d_out, int out_size, void* d_ws, size_t ws_size,
                              hipStream_t stream) {
  const float* x = (const float*)d_in[0];
  const float* W = (const float*)d_in[1];
  float* y = (float*)d_out;
  const int B = in_sizes[0] / ROWLEN;   // 8192
  dim3 grid(B / (TILE_B * NITER), NDET);
  ensemble_linear_v7<<<grid, dim3(THREADS), 0, stream>>>(x, W, y);
}

// Round 8
// 29.564 us; speedup vs baseline: 1.1263x; 1.0164x over previous
//
#include <hip/hip_runtime.h>

// Problem constants (fixed by reference setup_inputs): D=32 detectors,
// in_s = out_s = 64, row stride 2048 floats, B = 8192.
#define NDET    32
#define SEG     64
#define ROWLEN  2048
#define DGRP    4                 // detectors per block
#define XCOLS   (DGRP * SEG)      // 256 f32 = 1KB contiguous per row
#define TILE_R  64                // rows per block
#define THREADS 256
#define XLSTR   264               // x LDS row stride (bf16)
#define WLSTR   72                // W LDS o-row stride (bf16)

typedef __bf16 bf16x8 __attribute__((ext_vector_type(8)));
typedef __bf16 bf16x4 __attribute__((ext_vector_type(4)));
typedef float  f32x4  __attribute__((ext_vector_type(4)));

__device__ __forceinline__ bf16x4 cvt4(f32x4 a) {
  bf16x4 r;
  r[0] = (__bf16)a[0]; r[1] = (__bf16)a[1]; r[2] = (__bf16)a[2]; r[3] = (__bf16)a[3];
  return r;
}

// y[b, d*64+o] = sum_i x[b, d*64+i] * W[d*64+o, d*64+i]
//
// v8: DRAM-page-locality test. Each block covers 64 rows x 4 detectors, so
// every x access is a FULL 1KB contiguous row window (one wave instruction
// = 64 lanes x 16B = 1KB, one instr per row) instead of 256B chunks 8KB
// apart. W for the 4 detectors staged to LDS via the r4-proven coalesced
// mapping. One barrier; swapped-operand MFMA (D = W . x^T) as verified.
__global__ __launch_bounds__(THREADS) void ensemble_linear_v8(
    const float* __restrict__ x, const float* __restrict__ W,
    float* __restrict__ y) {
  const int dg     = blockIdx.y;
  const int dbase0 = dg * XCOLS;           // x/y column base; W row/col base
  const int r0     = blockIdx.x * TILE_R;
  const int t      = threadIdx.x;
  const int lane   = t & 63;
  const int wid    = t >> 6;               // 0..3
  const int rq  = lane >> 4;               // W staging: o-row within quad
  const int c4  = lane & 15;               // W staging: 16B chunk
  const int m16 = lane & 15;               // fragment M/N index
  const int kg  = lane >> 4;               // fragment k-group

  __shared__ __bf16 xls[TILE_R * XLSTR];        // 33792 B
  __shared__ __bf16 wls[DGRP * SEG * WLSTR];    // 36864 B

  // ---- x loads first (HBM stream): one full 1KB row window per instr ----
  f32x4 xv[16];
#pragma unroll
  for (int p = 0; p < 16; ++p) {
    const int row = p * 4 + wid;
    xv[p] = *(const f32x4*)(x + (size_t)(r0 + row) * ROWLEN + dbase0 + lane * 4);
  }

  // ---- W loads (L2-hot): coalesced 256B windows, 4 o-rows per instr ----
  // wave wid handles detector q = wid; o = p*4 + rq.
  f32x4 wv[16];
#pragma unroll
  for (int p = 0; p < 16; ++p) {
    const int o = p * 4 + rq;
    wv[p] = *(const f32x4*)(W + (size_t)(dbase0 + wid * SEG + o) * ROWLEN
                              + dbase0 + wid * SEG + c4 * 4);
  }

  // ---- stage x (waits only on x loads), then W ----
#pragma unroll
  for (int p = 0; p < 16; ++p) {
    const int row = p * 4 + wid;
    *(bf16x4*)(&xls[row * XLSTR + lane * 4]) = cvt4(xv[p]);
  }
#pragma unroll
  for (int p = 0; p < 16; ++p) {
    const int o = p * 4 + rq;
    *(bf16x4*)(&wls[(wid * SEG + o) * WLSTR + c4 * 4]) = cvt4(wv[p]);
  }

  __syncthreads();

  // ---- compute: wave owns rows [wid*16, wid*16+16) x 4 detectors ----
  const int rbase = wid * 16;
#pragma unroll
  for (int q = 0; q < DGRP; ++q) {
    bf16x8 a0 = *(const bf16x8*)(&xls[(rbase + m16) * XLSTR + q * SEG + kg * 8]);       // k 0..31
    bf16x8 a1 = *(const bf16x8*)(&xls[(rbase + m16) * XLSTR + q * SEG + 32 + kg * 8]);  // k 32..63

    float* yp = y + (size_t)(r0 + rbase + m16) * ROWLEN + dbase0 + q * SEG + kg * 4;
#pragma unroll
    for (int g = 0; g < 4; ++g) {
      bf16x8 w0 = *(const bf16x8*)(&wls[(q * SEG + g * 16 + m16) * WLSTR + kg * 8]);
      bf16x8 w1 = *(const bf16x8*)(&wls[(q * SEG + g * 16 + m16) * WLSTR + 32 + kg * 8]);
      f32x4 acc = (f32x4){0.f, 0.f, 0.f, 0.f};
      acc = __builtin_amdgcn_mfma_f32_16x16x32_bf16(w0, a0, acc, 0, 0, 0);
      acc = __builtin_amdgcn_mfma_f32_16x16x32_bf16(w1, a1, acc, 0, 0, 0);
      *(f32x4*)(yp + g * 16) = acc;
    }
  }
}

extern "C" void kernel_launch(void* const* d_in, const int* in_sizes, int n_in,
                              void* d_out, int out_size, void* d_ws, size_t ws_size,
                              hipStream_t stream) {
  const float* x = (const float*)d_in[0];
  const float* W = (const float*)d_in[1];
  float* y = (float*)d_out;
  const int B = in_sizes[0] / ROWLEN;   // 8192
  dim3 grid(B / TILE_R, NDET / DGRP);
  ensemble_linear_v8<<<grid, dim3(THREADS), 0, stream>>>(x, W, y);
}

// Round 9
// 26.909 us; speedup vs baseline: 1.2374x; 1.0987x over previous
//
#include <hip/hip_runtime.h>

// Problem constants (fixed by reference setup_inputs): D=32 detectors,
// in_s = out_s = 64, row stride 2048 floats, B = 8192.
#define NDET    32
#define SEG     64
#define ROWLEN  2048
#define TILE_B  128
#define THREADS 256
#define XSTR    72   // x LDS row stride, bf16 (144B, 16B-aligned, padded)
#define WSTR    72   // W LDS row stride, bf16
#define YSTR    68   // y LDS row stride, f32 (272B, 16B-aligned, padded)

typedef __bf16 bf16x8 __attribute__((ext_vector_type(8)));
typedef __bf16 bf16x4 __attribute__((ext_vector_type(4)));
typedef float  f32x4  __attribute__((ext_vector_type(4)));

__device__ __forceinline__ bf16x4 cvt4(f32x4 a) {
  bf16x4 r;
  r[0] = (__bf16)a[0]; r[1] = (__bf16)a[1]; r[2] = (__bf16)a[2]; r[3] = (__bf16)a[3];
  return r;
}

// y[b, d*64+o] = sum_i x[b, d*64+i] * W[d*64+o, d*64+i]
//
// v9 = r4 skeleton + LDS OUTPUT TRANSPOSE (the one new variable).
// r4's stores scatter 64B chunks across 16 rows 8KB apart (fixed by the
// MFMA C/D layout). Here accs go to an LDS y-tile first; the read-back
// pass stores with the coalesced optimum: each 16-lane group writes one
// COMPLETE 256B row window (4 rows = 1KB per instruction). Same store
// instruction count as r4 -- only the HBM address pattern changes.
// LDS is a union: phase A = x(18432B)+W(9216B), phase B = y(34816B).
__global__ __launch_bounds__(THREADS) void ensemble_linear_v9(
    const float* __restrict__ x, const float* __restrict__ W,
    float* __restrict__ y) {
  const int d     = blockIdx.y;
  const int b0    = blockIdx.x * TILE_B;
  const int t     = threadIdx.x;
  const int lane  = t & 63;
  const int wid   = t >> 6;        // 0..3
  const int dbase = d * SEG;

  const int rq  = lane >> 4;       // staging: row within 4-row quad
  const int c4  = lane & 15;       // staging: 16B chunk within 256B row
  const int m16 = lane & 15;       // fragment M/N index
  const int kg  = lane >> 4;       // fragment k-group

  __shared__ __align__(16) unsigned char smem[TILE_B * YSTR * 4];  // 34816B
  __bf16* xls = (__bf16*)smem;                 // [128][XSTR]
  __bf16* wls = (__bf16*)(smem + TILE_B * XSTR * 2);  // [64][WSTR]
  float*  yls = (float*)smem;                  // [128][YSTR] (phase B)

  // ---- issue x loads (coalesced: 4 complete 256B row windows / instr) ----
  f32x4 xv[8];
#pragma unroll
  for (int p = 0; p < 8; ++p) {
    const int row = wid * 32 + p * 4 + rq;
    xv[p] = *(const f32x4*)(x + (size_t)(b0 + row) * ROWLEN + dbase + c4 * 4);
  }

  // ---- issue W loads (same coalesced mapping; L2-hot) ----
  f32x4 wv[4];
#pragma unroll
  for (int p = 0; p < 4; ++p) {
    const int o = wid * 16 + p * 4 + rq;
    wv[p] = *(const f32x4*)(W + (size_t)(dbase + o) * ROWLEN + dbase + c4 * 4);
  }

  // ---- stage to LDS (bf16) ----
#pragma unroll
  for (int p = 0; p < 8; ++p) {
    const int row = wid * 32 + p * 4 + rq;
    *(bf16x4*)(&xls[row * XSTR + c4 * 4]) = cvt4(xv[p]);
  }
#pragma unroll
  for (int p = 0; p < 4; ++p) {
    const int o = wid * 16 + p * 4 + rq;
    *(bf16x4*)(&wls[o * WSTR + c4 * 4]) = cvt4(wv[p]);
  }

  __syncthreads();   // barrier 1: tiles staged

  // ---- fragment reads (ALL LDS reads happen before barrier 2) ----
  bf16x8 wfrag[4][2];
#pragma unroll
  for (int g = 0; g < 4; ++g)
#pragma unroll
    for (int kh = 0; kh < 2; ++kh)
      wfrag[g][kh] = *(const bf16x8*)(&wls[(g * 16 + m16) * WSTR + kh * 32 + kg * 8]);

  bf16x8 afrag[2][2];   // [s][kh]; wave owns rows [wid*32, wid*32+32)
#pragma unroll
  for (int s = 0; s < 2; ++s) {
    const int rbase = wid * 32 + s * 16;
    afrag[s][0] = *(const bf16x8*)(&xls[(rbase + m16) * XSTR + kg * 8]);
    afrag[s][1] = *(const bf16x8*)(&xls[(rbase + m16) * XSTR + 32 + kg * 8]);
  }

  __syncthreads();   // barrier 2: safe to overlay y onto x/W region

  // ---- MFMA + scatter accs to LDS y-tile (wave-private rows) ----
  // Swapped-operand MFMA (r3-verified): D = W_tile . x_tile^T.
  // acc(s,g): y row = wid*32 + s*16 + m16, cols g*16 + kg*4 .. +3.
#pragma unroll
  for (int s = 0; s < 2; ++s) {
    const int rbase = wid * 32 + s * 16;
#pragma unroll
    for (int g = 0; g < 4; ++g) {
      f32x4 acc = (f32x4){0.f, 0.f, 0.f, 0.f};
      acc = __builtin_amdgcn_mfma_f32_16x16x32_bf16(wfrag[g][0], afrag[s][0], acc, 0, 0, 0);
      acc = __builtin_amdgcn_mfma_f32_16x16x32_bf16(wfrag[g][1], afrag[s][1], acc, 0, 0, 0);
      *(f32x4*)(&yls[(rbase + m16) * YSTR + g * 16 + kg * 4]) = acc;
    }
  }

  // Wave-private region: our ds_writes retired before our ds_reads issue.
  asm volatile("s_waitcnt lgkmcnt(0)" ::: "memory");
  __builtin_amdgcn_sched_barrier(0);

  // ---- coalesced y store: 16-lane group = one complete 256B row window ----
#pragma unroll
  for (int p = 0; p < 8; ++p) {
    const int row = wid * 32 + p * 4 + rq;
    f32x4 v = *(const f32x4*)(&yls[row * YSTR + c4 * 4]);
    *(f32x4*)(y + (size_t)(b0 + row) * ROWLEN + dbase + c4 * 4) = v;
  }
}

extern "C" void kernel_launch(void* const* d_in, const int* in_sizes, int n_in,
                              void* d_out, int out_size, void* d_ws, size_t ws_size,
                              hipStream_t stream) {
  const float* x = (const float*)d_in[0];
  const float* W = (const float*)d_in[1];
  float* y = (float*)d_out;
  const int B = in_sizes[0] / ROWLEN;   // 8192
  dim3 grid(B / TILE_B, NDET);
  ensemble_linear_v9<<<grid, dim3(THREADS), 0, stream>>>(x, W, y);
}